// Round 3
// baseline (364.050 us; speedup 1.0000x reference)
//
#include <hip/hip_runtime.h>

#define BATCH   128
#define NUM_IN  4096
#define LVL     8
#define HID     32768
#define KH      32
#define OUTN    256
#define KOUT    64
#define SCALEA  4.9f

// act is stored node-major as bf16: act[node][b], 2B each, 256B per node.
// Viewed as uint: 64 uints per node, lane i holds batch {2i, 2i+1}.

__device__ __forceinline__ unsigned short f2bf(float f) {
    unsigned u = __float_as_uint(f);
    u += 0x7FFFu + ((u >> 16) & 1u);   // round-to-nearest-even
    return (unsigned short)(u >> 16);
}
__device__ __forceinline__ float bf_lo(unsigned u) { return __uint_as_float(u << 16); }
__device__ __forceinline__ float bf_hi(unsigned u) { return __uint_as_float(u & 0xFFFF0000u); }

// ---------------------------------------------------------------------------
// Transpose x [B, NUM_IN] f32 -> act [node][b] bf16 (packed pairs as uint)
// ---------------------------------------------------------------------------
__global__ __launch_bounds__(256) void transpose_x(const float* __restrict__ x,
                                                   unsigned* __restrict__ actu) {
    __shared__ float lds[64][129];
    const int n0 = blockIdx.x * 64;
    const int t  = threadIdx.x;
    #pragma unroll
    for (int it = 0; it < 32; ++it) {
        int i = it * 256 + t;
        int b = i >> 6;
        int n = i & 63;
        lds[n][b] = x[b * NUM_IN + n0 + n];
    }
    __syncthreads();
    #pragma unroll
    for (int it = 0; it < 16; ++it) {
        int i  = it * 256 + t;      // 0..4095 : 64 nodes x 64 uint-pairs
        int n  = i >> 6;
        int bp = i & 63;
        unsigned lo = f2bf(lds[n][2 * bp]);
        unsigned hi = f2bf(lds[n][2 * bp + 1]);
        actu[(n0 + n) * 64 + bp] = lo | (hi << 16);
    }
}

// ---------------------------------------------------------------------------
// One hidden level: one wave per hidden unit; wave-uniform idx/w (scalar
// loads); each lane owns 2 batch elements packed in one uint (256B coalesced
// gather per (h,k)). All 32 gathers are issued into a register array BEFORE
// any use -> 32 outstanding loads/wave for latency hiding. u[32]+overhead
// stays under the 64-VGPR occupancy cliff (8 waves/SIMD).
// ---------------------------------------------------------------------------
__global__ __launch_bounds__(256) void hidden_level(unsigned* __restrict__ actu,
                                                    const int* __restrict__ idx,
                                                    const float* __restrict__ w,
                                                    int base) {
    const int lane = threadIdx.x & 63;
    int h = (blockIdx.x << 2) + (threadIdx.x >> 6);
    h = __builtin_amdgcn_readfirstlane(h);
    const int*   ip = idx + h * KH;
    const float* wp = w   + h * KH;

    // Phase 1: issue all 32 gathers (keep results resident in VGPRs).
    unsigned u[KH];
    #pragma unroll
    for (int k = 0; k < KH; ++k) {
        int j = __builtin_amdgcn_readfirstlane(ip[k]);
        u[k] = actu[(unsigned)j * 64 + lane];
    }

    // Phase 2: accumulate.
    float ax = 0.f, ay = 0.f;
    #pragma unroll
    for (int k = 0; k < KH; ++k) {
        float wk = wp[k];
        ax = fmaf(wk, bf_lo(u[k]), ax);
        ay = fmaf(wk, bf_hi(u[k]), ay);
    }

    float rx = 1.f / (1.f + __expf(-SCALEA * ax));
    float ry = 1.f / (1.f + __expf(-SCALEA * ay));
    unsigned lo = f2bf(rx), hi = f2bf(ry);
    actu[(unsigned)(base + h) * 64 + lane] = lo | (hi << 16);
}

// ---------------------------------------------------------------------------
// Output layer: one wave per output unit, KO=64; f32 output in out[b][o].
// Two chunks of 32 outstanding gathers each (stay under VGPR cliff).
// ---------------------------------------------------------------------------
__global__ __launch_bounds__(256) void output_layer(const unsigned* __restrict__ actu,
                                                    const int* __restrict__ idx,
                                                    const float* __restrict__ w,
                                                    float* __restrict__ out) {
    const int lane = threadIdx.x & 63;
    int o = (blockIdx.x << 2) + (threadIdx.x >> 6);
    o = __builtin_amdgcn_readfirstlane(o);
    const int*   ip = idx + o * KOUT;
    const float* wp = w   + o * KOUT;

    float ax = 0.f, ay = 0.f;
    #pragma unroll
    for (int c = 0; c < 2; ++c) {
        unsigned u[32];
        #pragma unroll
        for (int k = 0; k < 32; ++k) {
            int j = __builtin_amdgcn_readfirstlane(ip[c * 32 + k]);
            u[k] = actu[(unsigned)j * 64 + lane];
        }
        #pragma unroll
        for (int k = 0; k < 32; ++k) {
            float wk = wp[c * 32 + k];
            ax = fmaf(wk, bf_lo(u[k]), ax);
            ay = fmaf(wk, bf_hi(u[k]), ay);
        }
    }
    out[(2 * lane + 0) * OUTN + o] = 1.f / (1.f + __expf(-SCALEA * ax));
    out[(2 * lane + 1) * OUTN + o] = 1.f / (1.f + __expf(-SCALEA * ay));
}

extern "C" void kernel_launch(void* const* d_in, const int* in_sizes, int n_in,
                              void* d_out, int out_size, void* d_ws, size_t ws_size,
                              hipStream_t stream) {
    // setup_inputs() order: x, w_hidden, w_out, idx_hidden, idx_out
    const float* x          = (const float*)d_in[0];
    const float* w_hidden   = (const float*)d_in[1];
    const float* w_out      = (const float*)d_in[2];
    const int*   idx_hidden = (const int*)  d_in[3];
    const int*   idx_out    = (const int*)  d_in[4];
    float* out = (float*)d_out;

    // Activation buffer: (4096 + 262144) nodes x 128 batch x 2B bf16 = 68.2 MB
    unsigned* actu = (unsigned*)d_ws;

    transpose_x<<<NUM_IN / 64, 256, 0, stream>>>(x, actu);

    for (int l = 0; l < LVL; ++l) {
        hidden_level<<<HID / 4, 256, 0, stream>>>(
            actu,
            idx_hidden + (size_t)l * HID * KH,
            w_hidden   + (size_t)l * HID * KH,
            NUM_IN + l * HID);
    }

    output_layer<<<OUTN / 4, 256, 0, stream>>>(actu, idx_out, w_out, out);
}